// Round 20
// baseline (333.756 us; speedup 1.0000x reference)
//
#include <hip/hip_runtime.h>
#include <hip/hip_bf16.h>

using bf16 = __hip_bfloat16;
typedef __attribute__((ext_vector_type(8))) short short8v;
typedef __attribute__((ext_vector_type(4))) float f32x4;

#define MFMA16(a,b,c) __builtin_amdgcn_mfma_f32_16x16x32_bf16((a),(b),(c),0,0,0)

static constexpr int Bn = 8;
static constexpr int Ll = 56 * 56;      // 3136
static constexpr int Mrows = Bn * Ll;   // 25088

__device__ __forceinline__ void gload16(const void* g, void* l) {
  __builtin_amdgcn_global_load_lds(
      (const __attribute__((address_space(1))) void*)g,
      (__attribute__((address_space(3))) void*)l, 16, 0, 0);
}

__device__ __forceinline__ unsigned pack2(float a, float b) {
  unsigned ua = (unsigned)__bfloat16_as_ushort(__float2bfloat16(a));
  unsigned ub = (unsigned)__bfloat16_as_ushort(__float2bfloat16(b));
  return ua | (ub << 16);
}

// ---------------- LayerNorm: src f32 (row=256) -> bf16 ----------------
__global__ __launch_bounds__(256) void ln_kernel(const float* __restrict__ x,
    const float* __restrict__ g, const float* __restrict__ b,
    bf16* __restrict__ out) {
  int lane = threadIdx.x & 63;
  int row = blockIdx.x * 4 + (threadIdx.x >> 6);
  const float4 v = *reinterpret_cast<const float4*>(x + (size_t)row * 256 + lane * 4);
  float s = v.x + v.y + v.z + v.w;
  float sq = v.x * v.x + v.y * v.y + v.z * v.z + v.w * v.w;
#pragma unroll
  for (int m = 1; m < 64; m <<= 1) {
    s += __shfl_xor(s, m, 64);
    sq += __shfl_xor(sq, m, 64);
  }
  float mean = s * (1.0f / 256.0f);
  float rstd = rsqrtf(sq * (1.0f / 256.0f) - mean * mean + 1e-5f);
  const float4 gg = *reinterpret_cast<const float4*>(g + lane * 4);
  const float4 bb = *reinterpret_cast<const float4*>(b + lane * 4);
  bf16 o[4];
  o[0] = __float2bfloat16((v.x - mean) * rstd * gg.x + bb.x);
  o[1] = __float2bfloat16((v.y - mean) * rstd * gg.y + bb.y);
  o[2] = __float2bfloat16((v.z - mean) * rstd * gg.z + bb.z);
  o[3] = __float2bfloat16((v.w - mean) * rstd * gg.w + bb.w);
  *reinterpret_cast<uint2*>(out + (size_t)row * 256 + lane * 4) =
      *reinterpret_cast<const uint2*>(o);
}

// -------- packed weight transpose: 8 weights in ONE dispatch --------
struct WTDesc { const float* in; bf16* out; int K; int N; int bx0; };
struct WTArgs { WTDesc d[8]; };
__global__ __launch_bounds__(256) void wtrans_all(WTArgs a) {
  __shared__ float t[32][33];
  int gb = blockIdx.x;
  int i = 0;
#pragma unroll
  for (int j = 1; j < 8; j++) if (gb >= a.d[j].bx0) i = j;
  const float* in = a.d[i].in;
  bf16* out = a.d[i].out;
  int K = a.d[i].K, N = a.d[i].N;
  int local = gb - a.d[i].bx0;
  int nbk = K >> 5;
  int bx = local % nbk, by = local / nbk;
  int tx = threadIdx.x & 31, ty = threadIdx.x >> 5;
  int k0 = bx * 32, n0 = by * 32;
#pragma unroll
  for (int q = 0; q < 4; q++)
    t[ty + q * 8][tx] = in[(size_t)(k0 + ty + q * 8) * N + n0 + tx];
  __syncthreads();
#pragma unroll
  for (int q = 0; q < 4; q++)
    out[(size_t)(n0 + ty + q * 8) * K + k0 + tx] = __float2bfloat16(t[tx][ty + q * 8]);
}

// ---------------- GEMM: C = A(MxK) * Bt(NxK)^T, BM=64, BN in {64,128} ----
// counted-vmcnt pipeline + XCD swizzle. BN=64 -> LDS 32KB -> 5 blocks/CU.
template <int EPI, int BN>
__global__ __launch_bounds__(256) void gemm_kernel(
    const bf16* __restrict__ A, const bf16* __restrict__ Bt,
    const float* __restrict__ bias, const float* __restrict__ resid,
    void* __restrict__ outp, int M, int N, int K) {
  constexpr int NI = BN / 64;
  __shared__ bf16 Al[2][64 * 64];
  __shared__ bf16 Bl[2][BN * 64];
  int tid = threadIdx.x, lane = tid & 63, wid = tid >> 6;
  int lin = blockIdx.y * gridDim.x + blockIdx.x;
  int cpx = (gridDim.x * gridDim.y) >> 3;
  int swz = (lin & 7) * cpx + (lin >> 3);
  int bcol = swz % gridDim.x;
  int brow = swz / gridDim.x;
  f32x4 acc[4][NI];
#pragma unroll
  for (int i = 0; i < 4; i++)
#pragma unroll
    for (int j = 0; j < NI; j++) acc[i][j] = f32x4{0.f, 0.f, 0.f, 0.f};

  int r8 = lane >> 3;                      // row within 8-row chunk (= row&7)
  int c8 = ((lane & 7) ^ r8) * 8;          // pre-swizzled source column
  const bf16* ga0 = A + (size_t)(brow * 64 + r8) * K + c8;
  const bf16* gb0 = Bt + (size_t)(bcol * BN + r8) * K + c8;

  auto stage = [&](bf16* Ad, bf16* Bd, int kt) {
#pragma unroll
    for (int c = 0; c < 2; c++) {
      int chunk = c * 4 + wid;  // wave-uniform
      gload16(ga0 + (size_t)chunk * 8 * K + kt, Ad + chunk * 512);
    }
#pragma unroll
    for (int c = 0; c < BN / 32; c++) {
      int chunk = c * 4 + wid;
      gload16(gb0 + (size_t)chunk * 8 * K + kt, Bd + chunk * 512);
    }
  };

  stage(Al[0], Bl[0], 0);

  int lg = lane >> 4, ql = lane & 15, qx = ql & 7;
  int nk = K >> 6;
  for (int t = 0; t < nk; t++) {
    int cur = t & 1;
    if (t + 1 < nk) {
      stage(Al[cur ^ 1], Bl[cur ^ 1], (t + 1) * 64);
      if (BN == 64) asm volatile("s_waitcnt vmcnt(4)" ::: "memory");
      else          asm volatile("s_waitcnt vmcnt(6)" ::: "memory");
    } else {
      asm volatile("s_waitcnt vmcnt(0)" ::: "memory");
    }
    __builtin_amdgcn_s_barrier();
    bf16* Ac = Al[cur];
    bf16* Bc = Bl[cur];
#pragma unroll
    for (int kk = 0; kk < 64; kk += 32) {
      int slot = ((kk >> 3) + lg) ^ qx;    // physical 16B slot
      short8v av[4], bv[NI];
#pragma unroll
      for (int mi = 0; mi < 4; mi++)
        av[mi] = *reinterpret_cast<const short8v*>(
            &Ac[(mi * 16 + ql) * 64 + slot * 8]);
#pragma unroll
      for (int ni = 0; ni < NI; ni++)
        bv[ni] = *reinterpret_cast<const short8v*>(
            &Bc[(wid * (NI * 16) + ni * 16 + ql) * 64 + slot * 8]);
#pragma unroll
      for (int mi = 0; mi < 4; mi++)
#pragma unroll
        for (int ni = 0; ni < NI; ni++)
          acc[mi][ni] = MFMA16(av[mi], bv[ni], acc[mi][ni]);
    }
    __builtin_amdgcn_s_barrier();
  }

  int rowb = brow * 64 + ((lane >> 4) * 4);
  int colb = bcol * BN + wid * (NI * 16) + (lane & 15);
#pragma unroll
  for (int ni = 0; ni < NI; ni++) {
    int col = colb + ni * 16;
    float bvl = bias[col];
#pragma unroll
    for (int mi = 0; mi < 4; mi++) {
#pragma unroll
      for (int r = 0; r < 4; r++) {
        int row = rowb + mi * 16 + r;
        float v = acc[mi][ni][r] + bvl;
        if (EPI == 0) {
          ((bf16*)outp)[(size_t)row * N + col] = __float2bfloat16(v);
        } else if (EPI == 1) {
          float gv = 0.5f * v * (1.0f + erff(v * 0.70710678118654752f));
          ((bf16*)outp)[(size_t)row * N + col] = __float2bfloat16(gv);
        } else if (EPI == 2) {
          float* o = (float*)outp + (size_t)row * N + col;
          *o += v;
        } else {
          float sc = (col < 256) ? 0.25506275154111575f : 1.0f;
          ((bf16*)outp)[(size_t)row * N + col] = __float2bfloat16(v * sc);
        }
      }
    }
  }
}

// ------- GEMM (N=256 in one block) + residual + fused LayerNorm epilogue -------
// 512 threads / 8 waves: each wave owns 64x32 (acc 4x2). LDS 80KB -> 2 blocks/CU
// but 16 waves/CU (was 8). counted-vmcnt (5 loads/stage/wave) + XCD swizzle.
template <int RES>
__global__ __launch_bounds__(512) void gemm_ln_kernel(
    const bf16* __restrict__ A, const bf16* __restrict__ Bt,
    const float* __restrict__ bias, const float* __restrict__ resid,
    float* __restrict__ xout, const float* __restrict__ g,
    const float* __restrict__ b, bf16* __restrict__ lnout, int K) {
  __shared__ bf16 Al[2][64 * 64];    // 16 KB
  __shared__ bf16 Bl[2][256 * 64];   // 64 KB
  int tid = threadIdx.x, lane = tid & 63, wid = tid >> 6;   // wid 0..7
  int brow = (blockIdx.x & 7) * (gridDim.x >> 3) + (blockIdx.x >> 3);
  f32x4 acc[4][2];
#pragma unroll
  for (int i = 0; i < 4; i++)
#pragma unroll
    for (int j = 0; j < 2; j++) acc[i][j] = f32x4{0.f, 0.f, 0.f, 0.f};

  int r8 = lane >> 3;
  int c8 = ((lane & 7) ^ r8) * 8;
  const bf16* ga0 = A + (size_t)(brow * 64 + r8) * K + c8;
  const bf16* gb0 = Bt + (size_t)r8 * K + c8;

  auto stage = [&](bf16* Ad, bf16* Bd, int kt) {
    // A: 8 chunks, one per wave
    gload16(ga0 + (size_t)wid * 8 * K + kt, Ad + wid * 512);
    // B: 32 chunks, 4 per wave
#pragma unroll
    for (int c = 0; c < 4; c++) {
      int chunk = c * 8 + wid;
      gload16(gb0 + (size_t)chunk * 8 * K + kt, Bd + chunk * 512);
    }
  };

  stage(Al[0], Bl[0], 0);

  int lg = lane >> 4, ql = lane & 15, qx = ql & 7;
  int nk = K >> 6;
  for (int t = 0; t < nk; t++) {
    int cur = t & 1;
    if (t + 1 < nk) {
      stage(Al[cur ^ 1], Bl[cur ^ 1], (t + 1) * 64);
      asm volatile("s_waitcnt vmcnt(5)" ::: "memory");
    } else {
      asm volatile("s_waitcnt vmcnt(0)" ::: "memory");
    }
    __builtin_amdgcn_s_barrier();
    bf16* Ac = Al[cur];
    bf16* Bc = Bl[cur];
#pragma unroll
    for (int kk = 0; kk < 64; kk += 32) {
      int slot = ((kk >> 3) + lg) ^ qx;
      short8v av[4], bv[2];
#pragma unroll
      for (int mi = 0; mi < 4; mi++)
        av[mi] = *reinterpret_cast<const short8v*>(
            &Ac[(mi * 16 + ql) * 64 + slot * 8]);
#pragma unroll
      for (int ni = 0; ni < 2; ni++)
        bv[ni] = *reinterpret_cast<const short8v*>(
            &Bc[(wid * 32 + ni * 16 + ql) * 64 + slot * 8]);
#pragma unroll
      for (int mi = 0; mi < 4; mi++)
#pragma unroll
        for (int ni = 0; ni < 2; ni++)
          acc[mi][ni] = MFMA16(av[mi], bv[ni], acc[mi][ni]);
    }
    __builtin_amdgcn_s_barrier();
  }

  // ---- epilogue: x = base + acc + bias; row-wise LN over 256 cols ----
  float xv[4][2][4];
  float psum[4][4], psq[4][4];
#pragma unroll
  for (int mi = 0; mi < 4; mi++)
#pragma unroll
    for (int r = 0; r < 4; r++) { psum[mi][r] = 0.f; psq[mi][r] = 0.f; }

#pragma unroll
  for (int ni = 0; ni < 2; ni++) {
    int col = wid * 32 + ni * 16 + ql;
    float bvl = bias[col];
#pragma unroll
    for (int mi = 0; mi < 4; mi++) {
#pragma unroll
      for (int r = 0; r < 4; r++) {
        size_t row = (size_t)brow * 64 + mi * 16 + lg * 4 + r;
        float base = RES ? resid[row * 256 + col] : xout[row * 256 + col];
        float v = base + acc[mi][ni][r] + bvl;
        xv[mi][ni][r] = v;
        psum[mi][r] += v;
        psq[mi][r] += v * v;
      }
    }
  }
  // reduce across the 16-lane ql group (lanes sharing lg hold the same rows)
#pragma unroll
  for (int mi = 0; mi < 4; mi++)
#pragma unroll
    for (int r = 0; r < 4; r++) {
#pragma unroll
      for (int m = 1; m < 16; m <<= 1) {
        psum[mi][r] += __shfl_xor(psum[mi][r], m, 64);
        psq[mi][r] += __shfl_xor(psq[mi][r], m, 64);
      }
    }
  float* red = (float*)&Al[0][0];      // 64 rows x {8 sums, 8 sqs} = 4 KB
  float* red2 = red + 1024;            // 64 x {mean, rstd}
  if (ql == 0) {
#pragma unroll
    for (int mi = 0; mi < 4; mi++)
#pragma unroll
      for (int r = 0; r < 4; r++) {
        int lr = mi * 16 + lg * 4 + r;
        red[lr * 16 + wid] = psum[mi][r];
        red[lr * 16 + 8 + wid] = psq[mi][r];
      }
  }
  __syncthreads();
  if (tid < 64) {
    float s = 0.f, q = 0.f;
#pragma unroll
    for (int j = 0; j < 8; j++) {
      s += red[tid * 16 + j];
      q += red[tid * 16 + 8 + j];
    }
    float mean = s * (1.0f / 256.0f);
    float rstd = rsqrtf(q * (1.0f / 256.0f) - mean * mean + 1e-5f);
    red2[tid * 2] = mean;
    red2[tid * 2 + 1] = rstd;
  }
  __syncthreads();
#pragma unroll
  for (int mi = 0; mi < 4; mi++) {
#pragma unroll
    for (int r = 0; r < 4; r++) {
      int lr = mi * 16 + lg * 4 + r;
      float mean = red2[lr * 2], rstd = red2[lr * 2 + 1];
      size_t row = (size_t)brow * 64 + lr;
#pragma unroll
      for (int ni = 0; ni < 2; ni++) {
        int col = wid * 32 + ni * 16 + ql;
        float v = xv[mi][ni][r];
        xout[row * 256 + col] = v;
        lnout[row * 256 + col] =
            __float2bfloat16((v - mean) * rstd * g[col] + b[col]);
      }
    }
  }
}

// ---------------- Attention + fused LePE, ONE 1024-thread block per window-head ----
__global__ __launch_bounds__(1024, 4) void attn_kernel(const bf16* __restrict__ qkv,
    bf16* __restrict__ att,
    const float* __restrict__ lw0, const float* __restrict__ lb0,
    const float* __restrict__ lw1, const float* __restrict__ lb1) {
  __shared__ bf16 Kl[400 * 32];     // 25600 B
  __shared__ bf16 Vt[32 * 424];     // 27136 B
  __shared__ float wl[288];         // 1152 B
  __shared__ float bl[32];          // 128 B

  int tid = threadIdx.x, lane = tid & 63, wid = tid >> 6;
  int wh = blockIdx.x;              // 0..511
  int branch = wh >> 8;
  int head = wh & 3;
  int widx = (wh >> 2) & 63;
  int bimg = widx >> 3, g7 = widx & 7;
  int cb = branch * 128 + head * 32;
  size_t base = (size_t)bimg * Ll * 768;

  auto tok2l = [&](int t) -> int {
    if (branch == 0) { int d = t / 7;  return d * 56 + g7 * 7 + (t - d * 7); }
    else             { int d = t / 56; return (g7 * 7 + d) * 56 + (t - d * 56); }
  };

  // ---- stage K via global_load_lds, slot-swizzled through the SOURCE ----
#pragma unroll
  for (int it = 0; it < 2; it++) {
    int chunk = it * 1024 + tid;
    if (chunk < 1568) {             // 392 * 4
      int t = chunk >> 2;
      int sc = (((chunk & 3) ^ ((chunk >> 3) & 3))) * 8;
      gload16(qkv + base + (size_t)tok2l(t) * 768 + 256 + cb + sc,
              Kl + (size_t)(it * 1024 + wid * 64) * 8);
    }
  }
  // ---- stage swizzled V^T (register path; scatter) ----
  for (int idx = tid; idx < 1568; idx += 1024) {
    int t = idx >> 2, dq = (idx & 3) * 8;
    uint4 vv = *reinterpret_cast<const uint4*>(
        qkv + base + (size_t)tok2l(t) * 768 + 512 + cb + dq);
    const bf16* pv = reinterpret_cast<const bf16*>(&vv);
    int swz = (idx & 3) << 3;
#pragma unroll
    for (int j = 0; j < 8; j++) Vt[(dq + j) * 424 + (t ^ swz)] = pv[j];
  }
  bf16 z16 = __float2bfloat16(0.0f);
  if (tid < 768) {                   // zero logical pad cols 392..415
    int d = tid / 24, c = 392 + (tid - (tid / 24) * 24);
    Vt[d * 424 + (c ^ (((d >> 3) & 3) << 3))] = z16;
  }
  if (tid >= 704 && tid < 992) {
    const float* wsel = (branch ? lw1 : lw0) + head * 288;
    wl[tid - 704] = wsel[tid - 704];
  }
  if (tid >= 992) bl[tid - 992] = (branch ? lb1 : lb0)[head * 32 + tid - 992];
  __syncthreads();

  const f32x4 zz = {0.f, 0.f, 0.f, 0.f};
  int lg = lane >> 4;
  int ql = lane & 15;
  int sw0 = ((ql >> 3) & 1) << 3;
  int sw1 = sw0 + 16;
  int kslot = (lg ^ ((ql >> 1) & 3)) * 8;   // swizzled Kl slot

  auto epilogue = [&](int mt, float lsum, const f32x4& oA, const f32x4& oB) {
    int qo = mt * 16 + ql;
    if (qo >= 392) return;
    float inv = 1.0f / lsum;
    int wb_ = branch ? 56 : 7;
    int hb_ = branch ? 7 : 56;
    int lh = branch ? (qo / 56) : (qo / 7);
    int lw_ = qo - lh * wb_;
    float lep[8];
#pragma unroll
    for (int i = 0; i < 8; i++) lep[i] = bl[(i >> 2) * 16 + 4 * lg + (i & 3)];
#pragma unroll
    for (int dy = -1; dy <= 1; dy++) {
#pragma unroll
      for (int dx = -1; dx <= 1; dx++) {
        if ((unsigned)(lh + dy) < (unsigned)hb_ &&
            (unsigned)(lw_ + dx) < (unsigned)wb_) {
          int nt = qo + dy * wb_ + dx;
          int tap = (dy + 1) * 3 + (dx + 1);
#pragma unroll
          for (int i = 0; i < 8; i++) {
            int d = (i >> 2) * 16 + 4 * lg + (i & 3);
            lep[i] += wl[d * 9 + tap] *
                __bfloat162float(Vt[d * 424 + (nt ^ (((d >> 3) & 3) << 3))]);
          }
        }
      }
    }
    size_t ob = ((size_t)bimg * Ll + tok2l(qo)) * 256 + cb + 4 * lg;
    bf16 o4[4];
#pragma unroll
    for (int r = 0; r < 4; r++) o4[r] = __float2bfloat16(oA[r] * inv + lep[r]);
    *reinterpret_cast<uint2*>(att + ob) = *reinterpret_cast<const uint2*>(o4);
#pragma unroll
    for (int r = 0; r < 4; r++) o4[r] = __float2bfloat16(oB[r] * inv + lep[4 + r]);
    *reinterpret_cast<uint2*>(att + ob + 16) = *reinterpret_cast<const uint2*>(o4);
  };

  // ---- work split over 16 waves: each wave at most one sweep ----
  int mt0 = -1, mt1 = -1;
  if (wid < 9) { mt0 = 2 * wid; mt1 = 2 * wid + 1; }   // tiles 0..17
  else         { mt0 = 9 + wid; }                      // tiles 18..24

  if (mt0 >= 0) {
    int qr0 = mt0 * 16 + ql; if (qr0 > 391) qr0 = 391;
    int mtb = (mt1 >= 0) ? mt1 : mt0;
    int qr1 = mtb * 16 + ql; if (qr1 > 391) qr1 = 391;
    short8v qf0 = *reinterpret_cast<const short8v*>(
        qkv + base + (size_t)tok2l(qr0) * 768 + cb + lg * 8);
    short8v qf1 = *reinterpret_cast<const short8v*>(
        qkv + base + (size_t)tok2l(qr1) * 768 + cb + lg * 8);

    float ls0 = 0.f, ls1 = 0.f;
    f32x4 o00 = zz, o01 = zz, o10 = zz, o11 = zz;

#pragma unroll
    for (int c = 0; c < 13; c++) {
      short8v kf0 = *reinterpret_cast<const short8v*>(
          &Kl[(c * 32 + ql) * 32 + kslot]);
      f32x4 sA0, sB0, sA1, sB1;
      __builtin_amdgcn_s_setprio(1);
      sA0 = MFMA16(kf0, qf0, zz);
      sB0 = MFMA16(kf0, qf1, zz);
      __builtin_amdgcn_s_setprio(0);
      if (c < 12) {
        short8v kf1 = *reinterpret_cast<const short8v*>(
            &Kl[(c * 32 + 16 + ql) * 32 + kslot]);
        __builtin_amdgcn_s_setprio(1);
        sA1 = MFMA16(kf1, qf0, zz);
        sB1 = MFMA16(kf1, qf1, zz);
        __builtin_amdgcn_s_setprio(0);
      }
      float pA0[4], pA1[4], pB0[4], pB1[4];
#pragma unroll
      for (int r = 0; r < 4; r++) {
        if (c == 12) {
          pA0[r] = (lg < 2) ? exp2f(sA0[r]) : 0.f;
          pB0[r] = (lg < 2) ? exp2f(sB0[r]) : 0.f;
          pA1[r] = 0.f; pB1[r] = 0.f;
        } else {
          pA0[r] = exp2f(sA0[r]);
          pA1[r] = exp2f(sA1[r]);
          pB0[r] = exp2f(sB0[r]);
          pB1[r] = exp2f(sB1[r]);
        }
        ls0 += pA0[r] + pA1[r];
        ls1 += pB0[r] + pB1[r];
      }
      uint4 pwA, pwB;
      pwA.x = pack2(pA0[0], pA0[1]); pwA.y = pack2(pA0[2], pA0[3]);
      pwA.z = pack2(pA1[0], pA1[1]); pwA.w = pack2(pA1[2], pA1[3]);
      pwB.x = pack2(pB0[0], pB0[1]); pwB.y = pack2(pB0[2], pB0[3]);
      pwB.z = pack2(pB1[0], pB1[1]); pwB.w = pack2(pB1[2], pB1[3]);
      short8v pfA = *reinterpret_cast<const short8v*>(&pwA);
      short8v pfB = *reinterpret_cast<const short8v*>(&pwB);

      int col0 = c * 32 + 4 * lg;
      uint2 a0 = *reinterpret_cast<const uint2*>(&Vt[ql * 424 + (col0 ^ sw0)]);
      uint2 a1 = *reinterpret_cast<const uint2*>(&Vt[ql * 424 + ((col0 + 16) ^ sw0)]);
      uint2 b0 = *reinterpret_cast<const uint2*>(&Vt[(16 + ql) * 424 + (col0 ^ sw1)]);
      uint2 b1 = *reinterpret_cast<const uint2*>(&Vt[(16 + ql) * 424 + ((col0 + 16) ^ sw1)]);
      uint4 va = {a0.x, a0.y, a1.x, a1.y};
      uint4 vb = {b0.x, b0.y, b1.x, b1.y};
      short8v vf0 = *reinterpret_cast<const short8v*>(&va);
      short8v vf1 = *reinterpret_cast<const short8v*>(&vb);
      __builtin_amdgcn_s_setprio(1);
      o00 = MFMA16(vf0, pfA, o00);
      o01 = MFMA16(vf1, pfA, o01);
      o10 = MFMA16(vf0, pfB, o10);
      o11 = MFMA16(vf1, pfB, o11);
      __builtin_amdgcn_s_setprio(0);
    }

    ls0 += __shfl_xor(ls0, 16, 64);
    ls0 += __shfl_xor(ls0, 32, 64);
    ls1 += __shfl_xor(ls1, 16, 64);
    ls1 += __shfl_xor(ls1, 32, 64);

    epilogue(mt0, ls0, o00, o01);
    if (mt1 >= 0) epilogue(mt1, ls1, o10, o11);
  }
}

// ---------------- host ----------------
extern "C" void kernel_launch(void* const* d_in, const int* in_sizes, int n_in,
                              void* d_out, int out_size, void* d_ws, size_t ws_size,
                              hipStream_t stream) {
  const float* x_in    = (const float*)d_in[0];
  const float* ln1_g   = (const float*)d_in[1];
  const float* ln1_b   = (const float*)d_in[2];
  const float* qkv_w   = (const float*)d_in[3];
  const float* qkv_b   = (const float*)d_in[4];
  const float* lepe_w0 = (const float*)d_in[5];
  const float* lepe_b0 = (const float*)d_in[6];
  const float* lepe_w1 = (const float*)d_in[7];
  const float* lepe_b1 = (const float*)d_in[8];
  const float* proj_w  = (const float*)d_in[9];
  const float* proj_b  = (const float*)d_in[10];
  const float* ln2_g   = (const float*)d_in[11];
  const float* ln2_b   = (const float*)d_in[12];
  const float* fc1_w   = (const float*)d_in[13];
  const float* fc1_b   = (const float*)d_in[14];
  const float* fc2_w   = (const float*)d_in[15];
  const float* fc2_b   = (const float*)d_in[16];
  float* xf = (float*)d_out;

  char* ws = (char*)d_ws;
  bf16* wT   = (bf16*)ws;                                   // 3,145,728 B
  bf16* bufA = (bf16*)(ws + 3145728);                       // qkv / mlp-h
  bf16* imgB = (bf16*)(ws + 3145728 + 51380224);
  bf16* attB = (bf16*)(ws + 3145728 + 51380224 + 12845056);

  // packed weight transpose: one dispatch for all 8 weights
  {
    WTArgs a;
    int off = 0;
    for (int l = 0; l < 2; l++) {
      bf16* qkvT = wT + (size_t)l * 786432;
      WTDesc d[4] = {
        {qkv_w + l * 196608, qkvT,          256, 768,  0},
        {proj_w + l * 65536, qkvT + 196608, 256, 256,  0},
        {fc1_w + l * 262144, qkvT + 262144, 256, 1024, 0},
        {fc2_w + l * 262144, qkvT + 524288, 1024, 256, 0},
      };
      for (int j = 0; j < 4; j++) {
        d[j].bx0 = off;
        off += (d[j].K >> 5) * (d[j].N >> 5);
        a.d[l * 4 + j] = d[j];
      }
    }
    wtrans_all<<<off, 256, 0, stream>>>(a);
  }

  for (int l = 0; l < 2; l++) {
    bf16* qkvT = wT + (size_t)l * 786432;
    bf16* projT = qkvT + 196608;
    bf16* fc1T  = qkvT + 262144;
    bf16* fc2T  = qkvT + 524288;

    if (l == 0)
      ln_kernel<<<Mrows / 4, 256, 0, stream>>>(x_in, ln1_g, ln1_b, imgB);
    // else: imgB already holds LN1(x) from layer-0's fused fc2 epilogue

    gemm_kernel<4, 64><<<dim3(12, 392), 256, 0, stream>>>(imgB, qkvT, qkv_b + l * 768,
                                                          nullptr, bufA, Mrows, 768, 256);
    attn_kernel<<<512, 1024, 0, stream>>>(bufA, attB,
                                          lepe_w0 + l * 1152, lepe_b0 + l * 128,
                                          lepe_w1 + l * 1152, lepe_b1 + l * 128);
    // proj + residual + fused LN2 -> xf (f32) and imgB (bf16 LN2 out)
    if (l == 0) {
      gemm_ln_kernel<1><<<392, 512, 0, stream>>>(attB, projT, proj_b, x_in, xf,
                                                 ln2_g, ln2_b, imgB, 256);
    } else {
      gemm_ln_kernel<0><<<392, 512, 0, stream>>>(attB, projT, proj_b + 256, xf, xf,
                                                 ln2_g + 256, ln2_b + 256, imgB, 256);
    }
    gemm_kernel<1, 64><<<dim3(16, 392), 256, 0, stream>>>(imgB, fc1T, fc1_b + l * 1024,
                                                          nullptr, bufA, Mrows, 1024, 256);
    if (l == 0) {
      // fc2 + residual + fused LN1 of layer 1 -> xf and imgB
      gemm_ln_kernel<0><<<392, 512, 0, stream>>>(bufA, fc2T, fc2_b, xf, xf,
                                                 ln1_g + 256, ln1_b + 256, imgB, 1024);
    } else {
      gemm_kernel<2, 64><<<dim3(4, 392), 256, 0, stream>>>(bufA, fc2T, fc2_b + 256,
                                                           nullptr, xf, Mrows, 256, 1024);
    }
  }
}

// Round 21
// 329.684 us; speedup vs baseline: 1.0124x; 1.0124x over previous
//
#include <hip/hip_runtime.h>
#include <hip/hip_bf16.h>

using bf16 = __hip_bfloat16;
typedef __attribute__((ext_vector_type(8))) short short8v;
typedef __attribute__((ext_vector_type(4))) float f32x4;

#define MFMA16(a,b,c) __builtin_amdgcn_mfma_f32_16x16x32_bf16((a),(b),(c),0,0,0)

static constexpr int Bn = 8;
static constexpr int Ll = 56 * 56;      // 3136
static constexpr int Mrows = Bn * Ll;   // 25088

__device__ __forceinline__ void gload16(const void* g, void* l) {
  __builtin_amdgcn_global_load_lds(
      (const __attribute__((address_space(1))) void*)g,
      (__attribute__((address_space(3))) void*)l, 16, 0, 0);
}

__device__ __forceinline__ unsigned pack2(float a, float b) {
  unsigned ua = (unsigned)__bfloat16_as_ushort(__float2bfloat16(a));
  unsigned ub = (unsigned)__bfloat16_as_ushort(__float2bfloat16(b));
  return ua | (ub << 16);
}

// ---------------- LayerNorm: src f32 (row=256) -> bf16 ----------------
__global__ __launch_bounds__(256) void ln_kernel(const float* __restrict__ x,
    const float* __restrict__ g, const float* __restrict__ b,
    bf16* __restrict__ out) {
  int lane = threadIdx.x & 63;
  int row = blockIdx.x * 4 + (threadIdx.x >> 6);
  const float4 v = *reinterpret_cast<const float4*>(x + (size_t)row * 256 + lane * 4);
  float s = v.x + v.y + v.z + v.w;
  float sq = v.x * v.x + v.y * v.y + v.z * v.z + v.w * v.w;
#pragma unroll
  for (int m = 1; m < 64; m <<= 1) {
    s += __shfl_xor(s, m, 64);
    sq += __shfl_xor(sq, m, 64);
  }
  float mean = s * (1.0f / 256.0f);
  float rstd = rsqrtf(sq * (1.0f / 256.0f) - mean * mean + 1e-5f);
  const float4 gg = *reinterpret_cast<const float4*>(g + lane * 4);
  const float4 bb = *reinterpret_cast<const float4*>(b + lane * 4);
  bf16 o[4];
  o[0] = __float2bfloat16((v.x - mean) * rstd * gg.x + bb.x);
  o[1] = __float2bfloat16((v.y - mean) * rstd * gg.y + bb.y);
  o[2] = __float2bfloat16((v.z - mean) * rstd * gg.z + bb.z);
  o[3] = __float2bfloat16((v.w - mean) * rstd * gg.w + bb.w);
  *reinterpret_cast<uint2*>(out + (size_t)row * 256 + lane * 4) =
      *reinterpret_cast<const uint2*>(o);
}

// -------- packed weight transpose: 8 weights in ONE dispatch --------
struct WTDesc { const float* in; bf16* out; int K; int N; int bx0; };
struct WTArgs { WTDesc d[8]; };
__global__ __launch_bounds__(256) void wtrans_all(WTArgs a) {
  __shared__ float t[32][33];
  int gb = blockIdx.x;
  int i = 0;
#pragma unroll
  for (int j = 1; j < 8; j++) if (gb >= a.d[j].bx0) i = j;
  const float* in = a.d[i].in;
  bf16* out = a.d[i].out;
  int K = a.d[i].K, N = a.d[i].N;
  int local = gb - a.d[i].bx0;
  int nbk = K >> 5;
  int bx = local % nbk, by = local / nbk;
  int tx = threadIdx.x & 31, ty = threadIdx.x >> 5;
  int k0 = bx * 32, n0 = by * 32;
#pragma unroll
  for (int q = 0; q < 4; q++)
    t[ty + q * 8][tx] = in[(size_t)(k0 + ty + q * 8) * N + n0 + tx];
  __syncthreads();
#pragma unroll
  for (int q = 0; q < 4; q++)
    out[(size_t)(n0 + ty + q * 8) * K + k0 + tx] = __float2bfloat16(t[tx][ty + q * 8]);
}

// ---------------- GEMM: C = A(MxK) * Bt(NxK)^T, BM=64, BN in {64,128} ----
// counted-vmcnt pipeline + XCD swizzle. BN=64 -> LDS 32KB -> 5 blocks/CU.
template <int EPI, int BN>
__global__ __launch_bounds__(256) void gemm_kernel(
    const bf16* __restrict__ A, const bf16* __restrict__ Bt,
    const float* __restrict__ bias, const float* __restrict__ resid,
    void* __restrict__ outp, int M, int N, int K) {
  constexpr int NI = BN / 64;
  __shared__ bf16 Al[2][64 * 64];
  __shared__ bf16 Bl[2][BN * 64];
  int tid = threadIdx.x, lane = tid & 63, wid = tid >> 6;
  int lin = blockIdx.y * gridDim.x + blockIdx.x;
  int cpx = (gridDim.x * gridDim.y) >> 3;
  int swz = (lin & 7) * cpx + (lin >> 3);
  int bcol = swz % gridDim.x;
  int brow = swz / gridDim.x;
  f32x4 acc[4][NI];
#pragma unroll
  for (int i = 0; i < 4; i++)
#pragma unroll
    for (int j = 0; j < NI; j++) acc[i][j] = f32x4{0.f, 0.f, 0.f, 0.f};

  int r8 = lane >> 3;                      // row within 8-row chunk (= row&7)
  int c8 = ((lane & 7) ^ r8) * 8;          // pre-swizzled source column
  const bf16* ga0 = A + (size_t)(brow * 64 + r8) * K + c8;
  const bf16* gb0 = Bt + (size_t)(bcol * BN + r8) * K + c8;

  auto stage = [&](bf16* Ad, bf16* Bd, int kt) {
#pragma unroll
    for (int c = 0; c < 2; c++) {
      int chunk = c * 4 + wid;  // wave-uniform
      gload16(ga0 + (size_t)chunk * 8 * K + kt, Ad + chunk * 512);
    }
#pragma unroll
    for (int c = 0; c < BN / 32; c++) {
      int chunk = c * 4 + wid;
      gload16(gb0 + (size_t)chunk * 8 * K + kt, Bd + chunk * 512);
    }
  };

  stage(Al[0], Bl[0], 0);

  int lg = lane >> 4, ql = lane & 15, qx = ql & 7;
  int nk = K >> 6;
  for (int t = 0; t < nk; t++) {
    int cur = t & 1;
    if (t + 1 < nk) {
      stage(Al[cur ^ 1], Bl[cur ^ 1], (t + 1) * 64);
      if (BN == 64) asm volatile("s_waitcnt vmcnt(4)" ::: "memory");
      else          asm volatile("s_waitcnt vmcnt(6)" ::: "memory");
    } else {
      asm volatile("s_waitcnt vmcnt(0)" ::: "memory");
    }
    __builtin_amdgcn_s_barrier();
    bf16* Ac = Al[cur];
    bf16* Bc = Bl[cur];
#pragma unroll
    for (int kk = 0; kk < 64; kk += 32) {
      int slot = ((kk >> 3) + lg) ^ qx;    // physical 16B slot
      short8v av[4], bv[NI];
#pragma unroll
      for (int mi = 0; mi < 4; mi++)
        av[mi] = *reinterpret_cast<const short8v*>(
            &Ac[(mi * 16 + ql) * 64 + slot * 8]);
#pragma unroll
      for (int ni = 0; ni < NI; ni++)
        bv[ni] = *reinterpret_cast<const short8v*>(
            &Bc[(wid * (NI * 16) + ni * 16 + ql) * 64 + slot * 8]);
#pragma unroll
      for (int mi = 0; mi < 4; mi++)
#pragma unroll
        for (int ni = 0; ni < NI; ni++)
          acc[mi][ni] = MFMA16(av[mi], bv[ni], acc[mi][ni]);
    }
    __builtin_amdgcn_s_barrier();
  }

  int rowb = brow * 64 + ((lane >> 4) * 4);
  int colb = bcol * BN + wid * (NI * 16) + (lane & 15);
#pragma unroll
  for (int ni = 0; ni < NI; ni++) {
    int col = colb + ni * 16;
    float bvl = bias[col];
#pragma unroll
    for (int mi = 0; mi < 4; mi++) {
#pragma unroll
      for (int r = 0; r < 4; r++) {
        int row = rowb + mi * 16 + r;
        float v = acc[mi][ni][r] + bvl;
        if (EPI == 0) {
          ((bf16*)outp)[(size_t)row * N + col] = __float2bfloat16(v);
        } else if (EPI == 1) {
          float gv = 0.5f * v * (1.0f + erff(v * 0.70710678118654752f));
          ((bf16*)outp)[(size_t)row * N + col] = __float2bfloat16(gv);
        } else if (EPI == 2) {
          float* o = (float*)outp + (size_t)row * N + col;
          *o += v;
        } else {
          float sc = (col < 256) ? 0.25506275154111575f : 1.0f;
          ((bf16*)outp)[(size_t)row * N + col] = __float2bfloat16(v * sc);
        }
      }
    }
  }
}

// ------- GEMM (N=256 in one block) + residual + fused LayerNorm epilogue -------
template <int RES>
__global__ __launch_bounds__(256) void gemm_ln_kernel(
    const bf16* __restrict__ A, const bf16* __restrict__ Bt,
    const float* __restrict__ bias, const float* __restrict__ resid,
    float* __restrict__ xout, const float* __restrict__ g,
    const float* __restrict__ b, bf16* __restrict__ lnout, int K) {
  __shared__ bf16 Al[2][64 * 64];    // 16 KB
  __shared__ bf16 Bl[2][256 * 64];   // 64 KB
  int tid = threadIdx.x, lane = tid & 63, wid = tid >> 6;
  int brow = (blockIdx.x & 7) * (gridDim.x >> 3) + (blockIdx.x >> 3);
  f32x4 acc[4][4];
#pragma unroll
  for (int i = 0; i < 4; i++)
#pragma unroll
    for (int j = 0; j < 4; j++) acc[i][j] = f32x4{0.f, 0.f, 0.f, 0.f};

  int r8 = lane >> 3;
  int c8 = ((lane & 7) ^ r8) * 8;
  const bf16* ga0 = A + (size_t)(brow * 64 + r8) * K + c8;
  const bf16* gb0 = Bt + (size_t)r8 * K + c8;

  auto stage = [&](bf16* Ad, bf16* Bd, int kt) {
#pragma unroll
    for (int c = 0; c < 2; c++) {
      int chunk = c * 4 + wid;
      gload16(ga0 + (size_t)chunk * 8 * K + kt, Ad + chunk * 512);
    }
#pragma unroll
    for (int c = 0; c < 8; c++) {
      int chunk = c * 4 + wid;
      gload16(gb0 + (size_t)chunk * 8 * K + kt, Bd + chunk * 512);
    }
  };

  stage(Al[0], Bl[0], 0);

  int lg = lane >> 4, ql = lane & 15, qx = ql & 7;
  int nk = K >> 6;
  for (int t = 0; t < nk; t++) {
    int cur = t & 1;
    if (t + 1 < nk) {
      stage(Al[cur ^ 1], Bl[cur ^ 1], (t + 1) * 64);
      asm volatile("s_waitcnt vmcnt(10)" ::: "memory");
    } else {
      asm volatile("s_waitcnt vmcnt(0)" ::: "memory");
    }
    __builtin_amdgcn_s_barrier();
    bf16* Ac = Al[cur];
    bf16* Bc = Bl[cur];
#pragma unroll
    for (int kk = 0; kk < 64; kk += 32) {
      int slot = ((kk >> 3) + lg) ^ qx;
      short8v av[4], bv[4];
#pragma unroll
      for (int mi = 0; mi < 4; mi++)
        av[mi] = *reinterpret_cast<const short8v*>(
            &Ac[(mi * 16 + ql) * 64 + slot * 8]);
#pragma unroll
      for (int ni = 0; ni < 4; ni++)
        bv[ni] = *reinterpret_cast<const short8v*>(
            &Bc[(wid * 64 + ni * 16 + ql) * 64 + slot * 8]);
#pragma unroll
      for (int mi = 0; mi < 4; mi++)
#pragma unroll
        for (int ni = 0; ni < 4; ni++)
          acc[mi][ni] = MFMA16(av[mi], bv[ni], acc[mi][ni]);
    }
    __builtin_amdgcn_s_barrier();
  }

  // ---- epilogue: x = base + acc + bias; row-wise LN over 256 cols ----
  float xv[4][4][4];
  float psum[4][4], psq[4][4];
#pragma unroll
  for (int mi = 0; mi < 4; mi++)
#pragma unroll
    for (int r = 0; r < 4; r++) { psum[mi][r] = 0.f; psq[mi][r] = 0.f; }

#pragma unroll
  for (int ni = 0; ni < 4; ni++) {
    int col = wid * 64 + ni * 16 + ql;
    float bvl = bias[col];
#pragma unroll
    for (int mi = 0; mi < 4; mi++) {
#pragma unroll
      for (int r = 0; r < 4; r++) {
        size_t row = (size_t)brow * 64 + mi * 16 + lg * 4 + r;
        float base = RES ? resid[row * 256 + col] : xout[row * 256 + col];
        float v = base + acc[mi][ni][r] + bvl;
        xv[mi][ni][r] = v;
        psum[mi][r] += v;
        psq[mi][r] += v * v;
      }
    }
  }
#pragma unroll
  for (int mi = 0; mi < 4; mi++)
#pragma unroll
    for (int r = 0; r < 4; r++) {
#pragma unroll
      for (int m = 1; m < 16; m <<= 1) {
        psum[mi][r] += __shfl_xor(psum[mi][r], m, 64);
        psq[mi][r] += __shfl_xor(psq[mi][r], m, 64);
      }
    }
  float* red = (float*)&Al[0][0];
  float* red2 = red + 512;
  if (ql == 0) {
#pragma unroll
    for (int mi = 0; mi < 4; mi++)
#pragma unroll
      for (int r = 0; r < 4; r++) {
        int lr = mi * 16 + lg * 4 + r;
        red[lr * 8 + wid] = psum[mi][r];
        red[lr * 8 + 4 + wid] = psq[mi][r];
      }
  }
  __syncthreads();
  if (tid < 64) {
    float s = red[tid * 8] + red[tid * 8 + 1] + red[tid * 8 + 2] + red[tid * 8 + 3];
    float q = red[tid * 8 + 4] + red[tid * 8 + 5] + red[tid * 8 + 6] + red[tid * 8 + 7];
    float mean = s * (1.0f / 256.0f);
    float rstd = rsqrtf(q * (1.0f / 256.0f) - mean * mean + 1e-5f);
    red2[tid * 2] = mean;
    red2[tid * 2 + 1] = rstd;
  }
  __syncthreads();
#pragma unroll
  for (int mi = 0; mi < 4; mi++) {
#pragma unroll
    for (int r = 0; r < 4; r++) {
      int lr = mi * 16 + lg * 4 + r;
      float mean = red2[lr * 2], rstd = red2[lr * 2 + 1];
      size_t row = (size_t)brow * 64 + lr;
#pragma unroll
      for (int ni = 0; ni < 4; ni++) {
        int col = wid * 64 + ni * 16 + ql;
        float v = xv[mi][ni][r];
        xout[row * 256 + col] = v;
        lnout[row * 256 + col] =
            __float2bfloat16((v - mean) * rstd * g[col] + b[col]);
      }
    }
  }
}

// ---------------- Attention + fused LePE, ONE 1024-thread block per window-head ----
__global__ __launch_bounds__(1024, 4) void attn_kernel(const bf16* __restrict__ qkv,
    bf16* __restrict__ att,
    const float* __restrict__ lw0, const float* __restrict__ lb0,
    const float* __restrict__ lw1, const float* __restrict__ lb1) {
  __shared__ bf16 Kl[400 * 32];     // 25600 B
  __shared__ bf16 Vt[32 * 424];     // 27136 B
  __shared__ float wl[288];         // 1152 B
  __shared__ float bl[32];          // 128 B

  int tid = threadIdx.x, lane = tid & 63, wid = tid >> 6;
  int wh = blockIdx.x;              // 0..511
  int branch = wh >> 8;
  int head = wh & 3;
  int widx = (wh >> 2) & 63;
  int bimg = widx >> 3, g7 = widx & 7;
  int cb = branch * 128 + head * 32;
  size_t base = (size_t)bimg * Ll * 768;

  auto tok2l = [&](int t) -> int {
    if (branch == 0) { int d = t / 7;  return d * 56 + g7 * 7 + (t - d * 7); }
    else             { int d = t / 56; return (g7 * 7 + d) * 56 + (t - d * 56); }
  };

  // ---- stage K via global_load_lds, slot-swizzled through the SOURCE ----
#pragma unroll
  for (int it = 0; it < 2; it++) {
    int chunk = it * 1024 + tid;
    if (chunk < 1568) {             // 392 * 4
      int t = chunk >> 2;
      int sc = (((chunk & 3) ^ ((chunk >> 3) & 3))) * 8;
      gload16(qkv + base + (size_t)tok2l(t) * 768 + 256 + cb + sc,
              Kl + (size_t)(it * 1024 + wid * 64) * 8);
    }
  }
  // ---- stage swizzled V^T (register path; scatter) ----
  for (int idx = tid; idx < 1568; idx += 1024) {
    int t = idx >> 2, dq = (idx & 3) * 8;
    uint4 vv = *reinterpret_cast<const uint4*>(
        qkv + base + (size_t)tok2l(t) * 768 + 512 + cb + dq);
    const bf16* pv = reinterpret_cast<const bf16*>(&vv);
    int swz = (idx & 3) << 3;
#pragma unroll
    for (int j = 0; j < 8; j++) Vt[(dq + j) * 424 + (t ^ swz)] = pv[j];
  }
  bf16 z16 = __float2bfloat16(0.0f);
  if (tid < 768) {                   // zero logical pad cols 392..415
    int d = tid / 24, c = 392 + (tid - (tid / 24) * 24);
    Vt[d * 424 + (c ^ (((d >> 3) & 3) << 3))] = z16;
  }
  if (tid >= 704 && tid < 992) {
    const float* wsel = (branch ? lw1 : lw0) + head * 288;
    wl[tid - 704] = wsel[tid - 704];
  }
  if (tid >= 992) bl[tid - 992] = (branch ? lb1 : lb0)[head * 32 + tid - 992];
  __syncthreads();

  const f32x4 zz = {0.f, 0.f, 0.f, 0.f};
  int lg = lane >> 4;
  int ql = lane & 15;
  int sw0 = ((ql >> 3) & 1) << 3;
  int sw1 = sw0 + 16;
  int kslot = (lg ^ ((ql >> 1) & 3)) * 8;   // swizzled Kl slot

  auto epilogue = [&](int mt, float lsum, const f32x4& oA, const f32x4& oB) {
    int qo = mt * 16 + ql;
    if (qo >= 392) return;
    float inv = 1.0f / lsum;
    int wb_ = branch ? 56 : 7;
    int hb_ = branch ? 7 : 56;
    int lh = branch ? (qo / 56) : (qo / 7);
    int lw_ = qo - lh * wb_;
    float lep[8];
#pragma unroll
    for (int i = 0; i < 8; i++) lep[i] = bl[(i >> 2) * 16 + 4 * lg + (i & 3)];
#pragma unroll
    for (int dy = -1; dy <= 1; dy++) {
#pragma unroll
      for (int dx = -1; dx <= 1; dx++) {
        if ((unsigned)(lh + dy) < (unsigned)hb_ &&
            (unsigned)(lw_ + dx) < (unsigned)wb_) {
          int nt = qo + dy * wb_ + dx;
          int tap = (dy + 1) * 3 + (dx + 1);
#pragma unroll
          for (int i = 0; i < 8; i++) {
            int d = (i >> 2) * 16 + 4 * lg + (i & 3);
            lep[i] += wl[d * 9 + tap] *
                __bfloat162float(Vt[d * 424 + (nt ^ (((d >> 3) & 3) << 3))]);
          }
        }
      }
    }
    size_t ob = ((size_t)bimg * Ll + tok2l(qo)) * 256 + cb + 4 * lg;
    bf16 o4[4];
#pragma unroll
    for (int r = 0; r < 4; r++) o4[r] = __float2bfloat16(oA[r] * inv + lep[r]);
    *reinterpret_cast<uint2*>(att + ob) = *reinterpret_cast<const uint2*>(o4);
#pragma unroll
    for (int r = 0; r < 4; r++) o4[r] = __float2bfloat16(oB[r] * inv + lep[4 + r]);
    *reinterpret_cast<uint2*>(att + ob + 16) = *reinterpret_cast<const uint2*>(o4);
  };

  // ---- work split over 16 waves: each wave at most one sweep ----
  int mt0 = -1, mt1 = -1;
  if (wid < 9) { mt0 = 2 * wid; mt1 = 2 * wid + 1; }   // tiles 0..17
  else         { mt0 = 9 + wid; }                      // tiles 18..24

  if (mt0 >= 0) {
    int qr0 = mt0 * 16 + ql; if (qr0 > 391) qr0 = 391;
    int mtb = (mt1 >= 0) ? mt1 : mt0;
    int qr1 = mtb * 16 + ql; if (qr1 > 391) qr1 = 391;
    short8v qf0 = *reinterpret_cast<const short8v*>(
        qkv + base + (size_t)tok2l(qr0) * 768 + cb + lg * 8);
    short8v qf1 = *reinterpret_cast<const short8v*>(
        qkv + base + (size_t)tok2l(qr1) * 768 + cb + lg * 8);

    float ls0 = 0.f, ls1 = 0.f;
    f32x4 o00 = zz, o01 = zz, o10 = zz, o11 = zz;

#pragma unroll
    for (int c = 0; c < 13; c++) {
      short8v kf0 = *reinterpret_cast<const short8v*>(
          &Kl[(c * 32 + ql) * 32 + kslot]);
      f32x4 sA0, sB0, sA1, sB1;
      __builtin_amdgcn_s_setprio(1);
      sA0 = MFMA16(kf0, qf0, zz);
      sB0 = MFMA16(kf0, qf1, zz);
      __builtin_amdgcn_s_setprio(0);
      if (c < 12) {
        short8v kf1 = *reinterpret_cast<const short8v*>(
            &Kl[(c * 32 + 16 + ql) * 32 + kslot]);
        __builtin_amdgcn_s_setprio(1);
        sA1 = MFMA16(kf1, qf0, zz);
        sB1 = MFMA16(kf1, qf1, zz);
        __builtin_amdgcn_s_setprio(0);
      }
      float pA0[4], pA1[4], pB0[4], pB1[4];
#pragma unroll
      for (int r = 0; r < 4; r++) {
        if (c == 12) {
          pA0[r] = (lg < 2) ? exp2f(sA0[r]) : 0.f;
          pB0[r] = (lg < 2) ? exp2f(sB0[r]) : 0.f;
          pA1[r] = 0.f; pB1[r] = 0.f;
        } else {
          pA0[r] = exp2f(sA0[r]);
          pA1[r] = exp2f(sA1[r]);
          pB0[r] = exp2f(sB0[r]);
          pB1[r] = exp2f(sB1[r]);
        }
        ls0 += pA0[r] + pA1[r];
        ls1 += pB0[r] + pB1[r];
      }
      uint4 pwA, pwB;
      pwA.x = pack2(pA0[0], pA0[1]); pwA.y = pack2(pA0[2], pA0[3]);
      pwA.z = pack2(pA1[0], pA1[1]); pwA.w = pack2(pA1[2], pA1[3]);
      pwB.x = pack2(pB0[0], pB0[1]); pwB.y = pack2(pB0[2], pB0[3]);
      pwB.z = pack2(pB1[0], pB1[1]); pwB.w = pack2(pB1[2], pB1[3]);
      short8v pfA = *reinterpret_cast<const short8v*>(&pwA);
      short8v pfB = *reinterpret_cast<const short8v*>(&pwB);

      int col0 = c * 32 + 4 * lg;
      uint2 a0 = *reinterpret_cast<const uint2*>(&Vt[ql * 424 + (col0 ^ sw0)]);
      uint2 a1 = *reinterpret_cast<const uint2*>(&Vt[ql * 424 + ((col0 + 16) ^ sw0)]);
      uint2 b0 = *reinterpret_cast<const uint2*>(&Vt[(16 + ql) * 424 + (col0 ^ sw1)]);
      uint2 b1 = *reinterpret_cast<const uint2*>(&Vt[(16 + ql) * 424 + ((col0 + 16) ^ sw1)]);
      uint4 va = {a0.x, a0.y, a1.x, a1.y};
      uint4 vb = {b0.x, b0.y, b1.x, b1.y};
      short8v vf0 = *reinterpret_cast<const short8v*>(&va);
      short8v vf1 = *reinterpret_cast<const short8v*>(&vb);
      __builtin_amdgcn_s_setprio(1);
      o00 = MFMA16(vf0, pfA, o00);
      o01 = MFMA16(vf1, pfA, o01);
      o10 = MFMA16(vf0, pfB, o10);
      o11 = MFMA16(vf1, pfB, o11);
      __builtin_amdgcn_s_setprio(0);
    }

    ls0 += __shfl_xor(ls0, 16, 64);
    ls0 += __shfl_xor(ls0, 32, 64);
    ls1 += __shfl_xor(ls1, 16, 64);
    ls1 += __shfl_xor(ls1, 32, 64);

    epilogue(mt0, ls0, o00, o01);
    if (mt1 >= 0) epilogue(mt1, ls1, o10, o11);
  }
}

// ---------------- host ----------------
extern "C" void kernel_launch(void* const* d_in, const int* in_sizes, int n_in,
                              void* d_out, int out_size, void* d_ws, size_t ws_size,
                              hipStream_t stream) {
  const float* x_in    = (const float*)d_in[0];
  const float* ln1_g   = (const float*)d_in[1];
  const float* ln1_b   = (const float*)d_in[2];
  const float* qkv_w   = (const float*)d_in[3];
  const float* qkv_b   = (const float*)d_in[4];
  const float* lepe_w0 = (const float*)d_in[5];
  const float* lepe_b0 = (const float*)d_in[6];
  const float* lepe_w1 = (const float*)d_in[7];
  const float* lepe_b1 = (const float*)d_in[8];
  const float* proj_w  = (const float*)d_in[9];
  const float* proj_b  = (const float*)d_in[10];
  const float* ln2_g   = (const float*)d_in[11];
  const float* ln2_b   = (const float*)d_in[12];
  const float* fc1_w   = (const float*)d_in[13];
  const float* fc1_b   = (const float*)d_in[14];
  const float* fc2_w   = (const float*)d_in[15];
  const float* fc2_b   = (const float*)d_in[16];
  float* xf = (float*)d_out;

  char* ws = (char*)d_ws;
  bf16* wT   = (bf16*)ws;                                   // 3,145,728 B
  bf16* bufA = (bf16*)(ws + 3145728);                       // qkv / mlp-h
  bf16* imgB = (bf16*)(ws + 3145728 + 51380224);
  bf16* attB = (bf16*)(ws + 3145728 + 51380224 + 12845056);

  // packed weight transpose: one dispatch for all 8 weights
  {
    WTArgs a;
    int off = 0;
    for (int l = 0; l < 2; l++) {
      bf16* qkvT = wT + (size_t)l * 786432;
      WTDesc d[4] = {
        {qkv_w + l * 196608, qkvT,          256, 768,  0},
        {proj_w + l * 65536, qkvT + 196608, 256, 256,  0},
        {fc1_w + l * 262144, qkvT + 262144, 256, 1024, 0},
        {fc2_w + l * 262144, qkvT + 524288, 1024, 256, 0},
      };
      for (int j = 0; j < 4; j++) {
        d[j].bx0 = off;
        off += (d[j].K >> 5) * (d[j].N >> 5);
        a.d[l * 4 + j] = d[j];
      }
    }
    wtrans_all<<<off, 256, 0, stream>>>(a);
  }

  for (int l = 0; l < 2; l++) {
    bf16* qkvT = wT + (size_t)l * 786432;
    bf16* projT = qkvT + 196608;
    bf16* fc1T  = qkvT + 262144;
    bf16* fc2T  = qkvT + 524288;

    if (l == 0)
      ln_kernel<<<Mrows / 4, 256, 0, stream>>>(x_in, ln1_g, ln1_b, imgB);
    // else: imgB already holds LN1(x) from layer-0's fused fc2 epilogue

    gemm_kernel<4, 64><<<dim3(12, 392), 256, 0, stream>>>(imgB, qkvT, qkv_b + l * 768,
                                                          nullptr, bufA, Mrows, 768, 256);
    attn_kernel<<<512, 1024, 0, stream>>>(bufA, attB,
                                          lepe_w0 + l * 1152, lepe_b0 + l * 128,
                                          lepe_w1 + l * 1152, lepe_b1 + l * 128);
    // proj + residual + fused LN2 -> xf (f32) and imgB (bf16 LN2 out)
    if (l == 0) {
      gemm_ln_kernel<1><<<392, 256, 0, stream>>>(attB, projT, proj_b, x_in, xf,
                                                 ln2_g, ln2_b, imgB, 256);
    } else {
      gemm_ln_kernel<0><<<392, 256, 0, stream>>>(attB, projT, proj_b + 256, xf, xf,
                                                 ln2_g + 256, ln2_b + 256, imgB, 256);
    }
    gemm_kernel<1, 64><<<dim3(16, 392), 256, 0, stream>>>(imgB, fc1T, fc1_b + l * 1024,
                                                          nullptr, bufA, Mrows, 1024, 256);
    if (l == 0) {
      // fc2 + residual + fused LN1 of layer 1 -> xf and imgB
      gemm_ln_kernel<0><<<392, 256, 0, stream>>>(bufA, fc2T, fc2_b, xf, xf,
                                                 ln1_g + 256, ln1_b + 256, imgB, 1024);
    } else {
      gemm_kernel<2, 64><<<dim3(4, 392), 256, 0, stream>>>(bufA, fc2T, fc2_b + 256,
                                                           nullptr, xf, Mrows, 256, 1024);
    }
  }
}